// Round 16
// baseline (131.901 us; speedup 1.0000x reference)
//
#include <hip/hip_runtime.h>
#include <hip/hip_bf16.h>
#include <math.h>

#define QSCALE 0.18033688011112042f   /* 0.125 * log2(e) */

typedef __attribute__((ext_vector_type(4))) float f32x4;
typedef __attribute__((ext_vector_type(8))) short bf16x8;
typedef __attribute__((ext_vector_type(4))) short bf16x4;
typedef __attribute__((ext_vector_type(4))) float float4_t;
typedef __attribute__((ext_vector_type(4))) int int4_t;
typedef __attribute__((ext_vector_type(2))) unsigned int uint2_t;
typedef __attribute__((ext_vector_type(2))) unsigned long long u64x2;

typedef const __attribute__((address_space(1))) void gbl_cvoid;
typedef __attribute__((address_space(3))) void lds_void;

static __device__ __forceinline__ void gload16(const void* g, void* l){
  __builtin_amdgcn_global_load_lds((gbl_cvoid*)g, (lds_void*)l, 16, 0, 0);
}

static __device__ __forceinline__ unsigned short f2b(float f){
  unsigned int u = __builtin_bit_cast(unsigned int, f);
  u = (u + 0x7FFFu + ((u >> 16) & 1u)) >> 16;
  return (unsigned short)u;
}

// attention-side packed convert: output feeds ds_write (lgkm-interlocked), far
// from MFMAs — 10 passing rounds confirm this asm placement is safe.
static __device__ __forceinline__ unsigned int cvtpk_bf16(float a, float b){
  unsigned int r;
  asm("v_cvt_pk_bf16_f32 %0, %1, %2" : "=v"(r) : "v"(a), "v"(b));
  return r;
}

// exp2: single v_exp_f32 via builtin (compiler-visible, hazard-safe); fallback libm.
#if defined(__has_builtin)
#if __has_builtin(__builtin_amdgcn_exp2f)
#define EXP2R __builtin_amdgcn_exp2f
#endif
#endif
#ifndef EXP2R
#define EXP2R exp2f
#endif

// ---------------- fp32->bf16 cvt (7 tensors) + mask->bits, one dispatch ----------------
struct CvtArgs { const float* src[7]; unsigned short* dst[7]; };

__global__ __launch_bounds__(256) void cvt_kernel(CvtArgs a, const int* __restrict__ mask,
                                                  unsigned long long* __restrict__ mout){
  int y = blockIdx.y;
  if (y == 7){
    if (blockIdx.x >= 256) return;
    int w = blockIdx.x * 256 + threadIdx.x;      // = t*32 + (s>>6)
    const int* p = mask + (size_t)w * 64;
    unsigned long long bits = 0ull;
    #pragma unroll
    for (int j = 0; j < 64; j += 4){
      int4_t v4 = *(const int4_t*)(p + j);
      if (v4[0]) bits |= (1ull << (j + 0));
      if (v4[1]) bits |= (1ull << (j + 1));
      if (v4[2]) bits |= (1ull << (j + 2));
      if (v4[3]) bits |= (1ull << (j + 3));
    }
    mout[w] = bits;
    return;
  }
  int n4 = (y < 3) ? (4194304/4) : (1048576/4);
  int idx = blockIdx.x * 256 + threadIdx.x;
  if (idx >= n4) return;
  float4_t v = *(const float4_t*)(a.src[y] + (size_t)idx * 4);
  bf16x4 b; b[0]=(short)f2b(v[0]); b[1]=(short)f2b(v[1]); b[2]=(short)f2b(v[2]); b[3]=(short)f2b(v[3]);
  *(bf16x4*)(a.dst[y] + (size_t)idx * 4) = b;
}

// ---------------- QKV GEMM: BM=BN=128, BK=32 dbuf + COUNTED vmcnt (r15-proven) ----------
struct GemmArgs { const unsigned short* A[3]; const unsigned short* W[3];
                  const float* bias[3]; void* C[3]; };

__global__ __launch_bounds__(256) void gemm_qkv_kernel(GemmArgs ga)
{
  __shared__ unsigned short As[2*128*32];   // 2 x 8 KB
  __shared__ unsigned short Ws[2*128*32];   // 2 x 8 KB
  const int tid = threadIdx.x, lane = tid & 63, wid = tid >> 6;
  const int sel = blockIdx.y >> 3;
  const int n0  = (blockIdx.y & 7) * 128;
  const int m0  = blockIdx.x * 128;
  const unsigned short* A = ga.A[sel];
  const unsigned short* W = ga.W[sel];
  const float* bias = ga.bias[sel];
  const int wm = wid >> 1, wn = wid & 1;
  const int r16 = lane & 15, kg = lane >> 4;
  const int phA = (kg ^ ((r16 >> 1) & 3)) * 8;     // phys chunk offset (ushorts)
  const int sRow = tid >> 2;                        // 0..63 within a 64-row round
  const int sL   = (tid & 3) ^ ((tid >> 3) & 3);    // logical chunk (round-invariant)

  f32x4 acc[4][4];
  const f32x4 z4 = {0.f, 0.f, 0.f, 0.f};
  #pragma unroll
  for (int i = 0; i < 4; ++i)
    #pragma unroll
    for (int j = 0; j < 4; ++j) acc[i][j] = z4;

  // prologue: stage k-step 0 into buf 0 (4 loads/thread)
  #pragma unroll
  for (int i = 0; i < 2; ++i){
    gload16(A + (size_t)(m0 + i*64 + sRow) * 1024 + sL * 8, (char*)As + i*4096 + wid*1024);
    gload16(W + (size_t)(n0 + i*64 + sRow) * 1024 + sL * 8, (char*)Ws + i*4096 + wid*1024);
  }

#define GSTEP(CUR, IT)                                                                \
  {                                                                                   \
    if ((IT) < 31) {                                                                  \
      const int k1 = ((IT) + 1) * 32;                                                 \
      _Pragma("unroll")                                                               \
      for (int i = 0; i < 2; ++i){                                                    \
        gload16(A + (size_t)(m0 + i*64 + sRow) * 1024 + k1 + sL * 8,                  \
                (char*)As + ((CUR) ^ 1) * 8192 + i*4096 + wid*1024);                  \
        gload16(W + (size_t)(n0 + i*64 + sRow) * 1024 + k1 + sL * 8,                  \
                (char*)Ws + ((CUR) ^ 1) * 8192 + i*4096 + wid*1024);                  \
      }                                                                               \
      asm volatile("s_waitcnt vmcnt(4)" ::: "memory");                                \
    } else {                                                                          \
      asm volatile("s_waitcnt vmcnt(0)" ::: "memory");                                \
    }                                                                                 \
    __builtin_amdgcn_sched_barrier(0);                                                \
    __builtin_amdgcn_s_barrier();      /* all threads' buf-CUR loads complete */      \
    bf16x8 af[4], wf[4];                                                              \
    _Pragma("unroll")                                                                 \
    for (int mi = 0; mi < 4; ++mi)                                                    \
      af[mi] = *(const bf16x8*)(As + (CUR)*4096 + (wm*64 + mi*16 + r16)*32 + phA);    \
    _Pragma("unroll")                                                                 \
    for (int ni = 0; ni < 4; ++ni)                                                    \
      wf[ni] = *(const bf16x8*)(Ws + (CUR)*4096 + (wn*64 + ni*16 + r16)*32 + phA);    \
    __builtin_amdgcn_s_setprio(1);                                                    \
    _Pragma("unroll")                                                                 \
    for (int mi = 0; mi < 4; ++mi)                                                    \
      _Pragma("unroll")                                                               \
      for (int ni = 0; ni < 4; ++ni)                                                  \
        acc[mi][ni] = __builtin_amdgcn_mfma_f32_16x16x32_bf16(af[mi], wf[ni],         \
                                                              acc[mi][ni], 0, 0, 0); \
    __builtin_amdgcn_s_setprio(0);                                                    \
    __builtin_amdgcn_s_barrier();      /* reads done before buf-CUR overwrite */      \
  }

  for (int ii = 0; ii < 16; ++ii) {
    GSTEP(0, 2 * ii)
    GSTEP(1, 2 * ii + 1)
  }
#undef GSTEP

  #pragma unroll
  for (int mi = 0; mi < 4; ++mi){
    #pragma unroll
    for (int ni = 0; ni < 4; ++ni){
      int m = m0 + wm*64 + mi*16 + kg*4;
      int n = n0 + wn*64 + ni*16 + r16;
      float bv = bias[n];
      if (sel == 2){
        int bb = m >> 11, t = m & 2047, hh = n >> 6, d = n & 63;
        bf16x4 pk;
        #pragma unroll
        for (int r = 0; r < 4; ++r) pk[r] = (short)f2b(acc[mi][ni][r] + bv);
        *(bf16x4*)&((unsigned short*)ga.C[2])[((size_t)(bb*16 + hh) * 64 + d) * 2048 + t] = pk;
      } else {
        #pragma unroll
        for (int r = 0; r < 4; ++r){
          float v = acc[mi][ni][r] + bv;
          if (sel == 0) v *= QSCALE;
          int mm = m + r;
          int bb = mm >> 11, t = mm & 2047, hh = n >> 6, d = n & 63;
          ((unsigned short*)ga.C[sel])[(((size_t)(bb*16 + hh) * 2048 + t) << 6) + d] = f2b(v);
        }
      }
    }
  }
}

// ---------------- O-proj GEMM: BM=64, BN=128, BK=32 dbuf + counted vmcnt ----------------
__global__ __launch_bounds__(256) void gemm_o_kernel(const unsigned short* __restrict__ A,
    const unsigned short* __restrict__ W, const float* __restrict__ bias,
    float* __restrict__ C)
{
  __shared__ unsigned short As[2*64*32];    // 2 x 4 KB
  __shared__ unsigned short Ws[2*128*32];   // 2 x 8 KB
  const int tid = threadIdx.x, lane = tid & 63, wid = tid >> 6;
  const int m0 = blockIdx.x * 64;
  const int n0 = blockIdx.y * 128;
  const int wm = wid >> 1, wn = wid & 1;
  const int r16 = lane & 15, kg = lane >> 4;
  const int phA = (kg ^ ((r16 >> 1) & 3)) * 8;
  const int sRow = tid >> 2;                        // 0..63
  const int sL   = (tid & 3) ^ ((tid >> 3) & 3);

  f32x4 acc[2][4];
  const f32x4 z4 = {0.f, 0.f, 0.f, 0.f};
  #pragma unroll
  for (int i = 0; i < 2; ++i)
    #pragma unroll
    for (int j = 0; j < 4; ++j) acc[i][j] = z4;

  // prologue: stage k-step 0 into buf 0 (3 loads/thread)
  gload16(A + (size_t)(m0 + sRow) * 1024 + sL * 8, (char*)As + wid*1024);
  #pragma unroll
  for (int i = 0; i < 2; ++i)
    gload16(W + (size_t)(n0 + i*64 + sRow) * 1024 + sL * 8, (char*)Ws + i*4096 + wid*1024);

#define OSTEP(CUR, IT)                                                                \
  {                                                                                   \
    if ((IT) < 31) {                                                                  \
      const int k1 = ((IT) + 1) * 32;                                                 \
      gload16(A + (size_t)(m0 + sRow) * 1024 + k1 + sL * 8,                           \
              (char*)As + ((CUR) ^ 1) * 4096 + wid*1024);                             \
      _Pragma("unroll")                                                               \
      for (int i = 0; i < 2; ++i)                                                     \
        gload16(W + (size_t)(n0 + i*64 + sRow) * 1024 + k1 + sL * 8,                  \
                (char*)Ws + ((CUR) ^ 1) * 8192 + i*4096 + wid*1024);                  \
      asm volatile("s_waitcnt vmcnt(3)" ::: "memory");                                \
    } else {                                                                          \
      asm volatile("s_waitcnt vmcnt(0)" ::: "memory");                                \
    }                                                                                 \
    __builtin_amdgcn_sched_barrier(0);                                                \
    __builtin_amdgcn_s_barrier();                                                     \
    bf16x8 af[2], wf[4];                                                              \
    _Pragma("unroll")                                                                 \
    for (int mi = 0; mi < 2; ++mi)                                                    \
      af[mi] = *(const bf16x8*)(As + (CUR)*2048 + (wm*32 + mi*16 + r16)*32 + phA);    \
    _Pragma("unroll")                                                                 \
    for (int ni = 0; ni < 4; ++ni)                                                    \
      wf[ni] = *(const bf16x8*)(Ws + (CUR)*4096 + (wn*64 + ni*16 + r16)*32 + phA);    \
    __builtin_amdgcn_s_setprio(1);                                                    \
    _Pragma("unroll")                                                                 \
    for (int mi = 0; mi < 2; ++mi)                                                    \
      _Pragma("unroll")                                                               \
      for (int ni = 0; ni < 4; ++ni)                                                  \
        acc[mi][ni] = __builtin_amdgcn_mfma_f32_16x16x32_bf16(af[mi], wf[ni],         \
                                                              acc[mi][ni], 0, 0, 0); \
    __builtin_amdgcn_s_setprio(0);                                                    \
    __builtin_amdgcn_s_barrier();                                                     \
  }

  for (int ii = 0; ii < 16; ++ii) {
    OSTEP(0, 2 * ii)
    OSTEP(1, 2 * ii + 1)
  }
#undef OSTEP

  #pragma unroll
  for (int mi = 0; mi < 2; ++mi){
    #pragma unroll
    for (int ni = 0; ni < 4; ++ni){
      int m = m0 + wm*32 + mi*16 + kg*4;
      int n = n0 + wn*64 + ni*16 + r16;
      float bv = bias[n];
      #pragma unroll
      for (int r = 0; r < 4; ++r)
        C[(size_t)(m + r) * 1024 + n] = acc[mi][ni][r] + bv;
    }
  }
}

// ---------------- flash attention: counted-vmcnt pipeline (T4 ported) ----------------
// Per step: issue 4 gload_lds + 1 mask load (5 VMEM, program-order pinned by asm
// memory clobber) -> s_waitcnt vmcnt(5) retires ONLY the previous step's 5 ->
// s_barrier -> compute buf CUR -> s_barrier (reads done before CUR overwrite).
__global__ __launch_bounds__(512) void attn_kernel(const unsigned short* __restrict__ qh,
    const unsigned short* __restrict__ kh, const unsigned short* __restrict__ vhT,
    const unsigned long long* __restrict__ mbits, unsigned short* __restrict__ attnout)
{
  __shared__ short Ks[2][2][64][64];   // [buf][sub][s][d]
  __shared__ short Vs[2][2][64][64];   // [buf][sub][d][s]
  __shared__ short Ps[128][64];        // wave-private 16-row stripes
  const int tid = threadIdx.x, lane = tid & 63, wid = tid >> 6;
  const int bh = blockIdx.y;
  const int b = bh >> 4, h = bh & 15;
  const int t0 = blockIdx.x * 128;
  const int tw = t0 + wid * 16;
  const int r16 = lane & 15, kg = lane >> 4;
  const int x7 = r16 & 7;
  const int ph0 = (kg ^ x7) * 8;
  const int ph1 = ((kg + 4) ^ x7) * 8;
  const int sR = tid >> 3;             // 0..63
  const int sL = (tid & 7) ^ (sR & 7);

  const unsigned short* kbase = kh + (size_t)bh * 2048 * 64;
  const unsigned short* vtb   = vhT + (size_t)bh * 64 * 2048;
  const unsigned short* qbase = qh + ((size_t)bh * 2048 + tw) * 64;

  bf16x8 aq[2];
  aq[0] = *(const bf16x8*)(qbase + (size_t)r16 * 64 + kg * 8);
  aq[1] = *(const bf16x8*)(qbase + (size_t)r16 * 64 + 32 + kg * 8);

  const short ob = (short)0x3F80;
  const bf16x8 ones8 = {ob, ob, ob, ob, ob, ob, ob, ob};

  f32x4 o[4], o5;
  const f32x4 z4 = {0.f, 0.f, 0.f, 0.f};
  #pragma unroll
  for (int df = 0; df < 4; ++df) o[df] = z4;
  o5 = z4;

  const unsigned long long* mrow = mbits + (size_t)(tw + r16) * 32;
  const size_t koff = (size_t)sR * 64 + sL * 8;
  const size_t voff = (size_t)sR * 2048 + sL * 8;

  // prologue: stage KV block 0 into buf 0 (4 glds + 1 mask load; step 0 waits)
  #pragma unroll
  for (int i = 0; i < 2; ++i){
    gload16(kbase + (size_t)i * 4096 + koff, (char*)Ks + i * 8192 + wid * 1024);
    gload16(vtb + voff + i * 64,            (char*)Vs + i * 8192 + wid * 1024);
  }
  u64x2 mw = *(const u64x2*)(mrow);

#define ATTN_STEP(CUR, IT)                                                            \
  {                                                                                   \
    u64x2 mwn = mw;                                                                   \
    if ((IT) < 15) {                                                                  \
      const unsigned short* kc = kbase + (size_t)((IT) + 1) * 8192;                   \
      const unsigned short* vc = vtb + (size_t)((IT) + 1) * 128;                      \
      _Pragma("unroll")                                                               \
      for (int i = 0; i < 2; ++i){                                                    \
        gload16(kc + (size_t)i * 4096 + koff,                                         \
                (char*)Ks + ((CUR) ^ 1) * 16384 + i * 8192 + wid * 1024);             \
        gload16(vc + voff + i * 64,                                                   \
                (char*)Vs + ((CUR) ^ 1) * 16384 + i * 8192 + wid * 1024);             \
      }                                                                               \
      mwn = *(const u64x2*)(mrow + 2 * ((IT) + 1));                                   \
      asm volatile("s_waitcnt vmcnt(5)" ::: "memory");                                \
    } else {                                                                          \
      asm volatile("s_waitcnt vmcnt(0)" ::: "memory");                                \
    }                                                                                 \
    __builtin_amdgcn_sched_barrier(0);                                                \
    __builtin_amdgcn_s_barrier();      /* buf CUR fully staged for all waves */       \
    _Pragma("unroll")                                                                 \
    for (int sub = 0; sub < 2; ++sub){                                                \
      f32x4 sfr[4];                                                                   \
      __builtin_amdgcn_s_setprio(1);                                                  \
      _Pragma("unroll")                                                               \
      for (int sb = 0; sb < 4; ++sb){                                                 \
        bf16x8 bk0 = *(const bf16x8*)&Ks[CUR][sub][sb*16 + r16][ph0];                 \
        bf16x8 bk1 = *(const bf16x8*)&Ks[CUR][sub][sb*16 + r16][ph1];                 \
        f32x4 z = z4;                                                                 \
        z = __builtin_amdgcn_mfma_f32_16x16x32_bf16(bk0, aq[0], z, 0, 0, 0);          \
        z = __builtin_amdgcn_mfma_f32_16x16x32_bf16(bk1, aq[1], z, 0, 0, 0);          \
        sfr[sb] = z;                                                                  \
      }                                                                               \
      __builtin_amdgcn_s_setprio(0);                                                  \
      {                                                                               \
        unsigned long long mk = (~mw[sub]) >> (kg * 4);   /* 1 = keep */              \
        unsigned int wlo = (unsigned int)mk;                                          \
        unsigned int whi = (unsigned int)(mk >> 32);                                  \
        _Pragma("unroll")                                                             \
        for (int sb = 0; sb < 4; ++sb){                                               \
          unsigned int wd = (sb < 2) ? wlo : whi;                                     \
          float pf[4];                                                                \
          _Pragma("unroll")                                                           \
          for (int r = 0; r < 4; ++r){                                                \
            const int pos = (sb & 1) * 16 + r;                                        \
            unsigned int msk = (unsigned int)((int)(wd << (31 - pos)) >> 31);         \
            float e = EXP2R(sfr[sb][r]);                                              \
            pf[r] = __builtin_bit_cast(float,                                         \
                      __builtin_bit_cast(unsigned int, e) & msk);                     \
          }                                                                           \
          unsigned int lo = cvtpk_bf16(pf[0], pf[1]);                                 \
          unsigned int hi = cvtpk_bf16(pf[2], pf[3]);                                 \
          int phys = (sb * 2 + (kg >> 1)) ^ x7;                                       \
          uint2_t pk; pk[0] = lo; pk[1] = hi;                                         \
          *(uint2_t*)&Ps[wid*16 + r16][phys * 8 + (kg & 1) * 4] = pk;                 \
        }                                                                             \
      }                                                                               \
      bf16x8 pa0 = *(const bf16x8*)&Ps[wid*16 + r16][ph0];                            \
      bf16x8 pa1 = *(const bf16x8*)&Ps[wid*16 + r16][ph1];                            \
      __builtin_amdgcn_s_setprio(1);                                                  \
      _Pragma("unroll")                                                               \
      for (int df = 0; df < 4; ++df){                                                 \
        bf16x8 bv0 = *(const bf16x8*)&Vs[CUR][sub][df*16 + r16][ph0];                 \
        bf16x8 bv1 = *(const bf16x8*)&Vs[CUR][sub][df*16 + r16][ph1];                 \
        o[df] = __builtin_amdgcn_mfma_f32_16x16x32_bf16(pa0, bv0, o[df], 0, 0, 0);    \
        o[df] = __builtin_amdgcn_mfma_f32_16x16x32_bf16(pa1, bv1, o[df], 0, 0, 0);    \
      }                                                                               \
      o5 = __builtin_amdgcn_mfma_f32_16x16x32_bf16(pa0, ones8, o5, 0, 0, 0);          \
      o5 = __builtin_amdgcn_mfma_f32_16x16x32_bf16(pa1, ones8, o5, 0, 0, 0);          \
      __builtin_amdgcn_s_setprio(0);                                                  \
    }                                                                                 \
    __builtin_amdgcn_s_barrier();      /* reads done before buf-CUR overwrite */      \
    mw = mwn;                                                                         \
  }

  for (int ii = 0; ii < 8; ++ii) {
    ATTN_STEP(0, 2 * ii)
    ATTN_STEP(1, 2 * ii + 1)
  }
#undef ATTN_STEP

  // epilogue: every lane holds all 4 row-sums in o5
  float lv0 = 1.0f / o5[0];
  float lv1 = 1.0f / o5[1];
  float lv2 = 1.0f / o5[2];
  float lv3 = 1.0f / o5[3];
  #pragma unroll
  for (int df = 0; df < 4; ++df){
    int col = h*64 + df*16 + r16;
    int t = tw + kg*4;
    attnout[(size_t)(b * 2048 + t + 0) * 1024 + col] = (short)f2b(o[df][0] * lv0);
    attnout[(size_t)(b * 2048 + t + 1) * 1024 + col] = (short)f2b(o[df][1] * lv1);
    attnout[(size_t)(b * 2048 + t + 2) * 1024 + col] = (short)f2b(o[df][2] * lv2);
    attnout[(size_t)(b * 2048 + t + 3) * 1024 + col] = (short)f2b(o[df][3] * lv3);
  }
}

// ---------------- launch ----------------
extern "C" void kernel_launch(void* const* d_in, const int* in_sizes, int n_in,
                              void* d_out, int out_size, void* d_ws, size_t ws_size,
                              hipStream_t stream) {
  const float* q    = (const float*)d_in[0];
  const float* k    = (const float*)d_in[1];
  const float* v    = (const float*)d_in[2];
  const int*   mask = (const int*)d_in[3];
  const float* Wq = (const float*)d_in[4];  const float* bq = (const float*)d_in[5];
  const float* Wk = (const float*)d_in[6];  const float* bk = (const float*)d_in[7];
  const float* Wv = (const float*)d_in[8];  const float* bv = (const float*)d_in[9];
  const float* Wo = (const float*)d_in[10]; const float* bo = (const float*)d_in[11];

  char* ws = (char*)d_ws;
  unsigned short* qb   = (unsigned short*)(ws);                   // 8 MB [4096][1024] bf16
  unsigned short* kb   = (unsigned short*)(ws + 8388608);         // 8 MB
  unsigned short* vb   = (unsigned short*)(ws + 16777216);        // 8 MB
  unsigned short* Wqb  = (unsigned short*)(ws + 25165824);        // 2 MB
  unsigned short* Wkb  = (unsigned short*)(ws + 27262976);        // 2 MB
  unsigned short* Wvb  = (unsigned short*)(ws + 29360128);        // 2 MB
  unsigned short* Wob  = (unsigned short*)(ws + 31457280);        // 2 MB
  unsigned short* qhd  = (unsigned short*)(ws + 33554432);        // 8 MB [bh][t][64]
  unsigned short* khd  = (unsigned short*)(ws + 41943040);        // 8 MB [bh][s][64]
  unsigned short* vhT  = (unsigned short*)(ws + 50331648);        // 8 MB [bh][64][2048]
  unsigned long long* mbits = (unsigned long long*)(ws + 58720256); // 512 KB
  unsigned short* attno = qb;   // alias: qb dead after QKV GEMM

  CvtArgs ca;
  ca.src[0]=q;  ca.dst[0]=qb;  ca.src[1]=k;  ca.dst[1]=kb;  ca.src[2]=v;  ca.dst[2]=vb;
  ca.src[3]=Wq; ca.dst[3]=Wqb; ca.src[4]=Wk; ca.dst[4]=Wkb;
  ca.src[5]=Wv; ca.dst[5]=Wvb; ca.src[6]=Wo; ca.dst[6]=Wob;
  cvt_kernel<<<dim3(4096, 8), 256, 0, stream>>>(ca, mask, mbits);

  GemmArgs g0;
  g0.A[0]=qb; g0.A[1]=kb; g0.A[2]=vb;
  g0.W[0]=Wqb; g0.W[1]=Wkb; g0.W[2]=Wvb;
  g0.bias[0]=bq; g0.bias[1]=bk; g0.bias[2]=bv;
  g0.C[0]=qhd; g0.C[1]=khd; g0.C[2]=vhT;
  gemm_qkv_kernel<<<dim3(32, 24), 256, 0, stream>>>(g0);

  attn_kernel<<<dim3(16, 32), 512, 0, stream>>>(qhd, khd, vhT, mbits, attno);

  gemm_o_kernel<<<dim3(64, 8), 256, 0, stream>>>(attno, Wob, bo, (float*)d_out);
}

// Round 17
// 127.002 us; speedup vs baseline: 1.0386x; 1.0386x over previous
//
#include <hip/hip_runtime.h>
#include <hip/hip_bf16.h>
#include <math.h>

#define QSCALE 0.18033688011112042f   /* 0.125 * log2(e) */

typedef __attribute__((ext_vector_type(4))) float f32x4;
typedef __attribute__((ext_vector_type(8))) short bf16x8;
typedef __attribute__((ext_vector_type(4))) short bf16x4;
typedef __attribute__((ext_vector_type(4))) float float4_t;
typedef __attribute__((ext_vector_type(4))) int int4_t;
typedef __attribute__((ext_vector_type(2))) unsigned int uint2_t;
typedef __attribute__((ext_vector_type(2))) unsigned long long u64x2;

typedef const __attribute__((address_space(1))) void gbl_cvoid;
typedef __attribute__((address_space(3))) void lds_void;

static __device__ __forceinline__ void gload16(const void* g, void* l){
  __builtin_amdgcn_global_load_lds((gbl_cvoid*)g, (lds_void*)l, 16, 0, 0);
}

static __device__ __forceinline__ unsigned short f2b(float f){
  unsigned int u = __builtin_bit_cast(unsigned int, f);
  u = (u + 0x7FFFu + ((u >> 16) & 1u)) >> 16;
  return (unsigned short)u;
}

// attention-side packed convert: output feeds ds_write (lgkm-interlocked), far
// from MFMAs — 10 passing rounds confirm this asm placement is safe.
static __device__ __forceinline__ unsigned int cvtpk_bf16(float a, float b){
  unsigned int r;
  asm("v_cvt_pk_bf16_f32 %0, %1, %2" : "=v"(r) : "v"(a), "v"(b));
  return r;
}

// exp2: single v_exp_f32 via builtin (compiler-visible, hazard-safe); fallback libm.
#if defined(__has_builtin)
#if __has_builtin(__builtin_amdgcn_exp2f)
#define EXP2R __builtin_amdgcn_exp2f
#endif
#endif
#ifndef EXP2R
#define EXP2R exp2f
#endif

// ---------------- fp32->bf16 cvt (7 tensors) + mask->bits, one dispatch ----------------
struct CvtArgs { const float* src[7]; unsigned short* dst[7]; };

__global__ __launch_bounds__(256) void cvt_kernel(CvtArgs a, const int* __restrict__ mask,
                                                  unsigned long long* __restrict__ mout){
  int y = blockIdx.y;
  if (y == 7){
    if (blockIdx.x >= 256) return;
    int w = blockIdx.x * 256 + threadIdx.x;      // = t*32 + (s>>6)
    const int* p = mask + (size_t)w * 64;
    unsigned long long bits = 0ull;
    #pragma unroll
    for (int j = 0; j < 64; j += 4){
      int4_t v4 = *(const int4_t*)(p + j);
      if (v4[0]) bits |= (1ull << (j + 0));
      if (v4[1]) bits |= (1ull << (j + 1));
      if (v4[2]) bits |= (1ull << (j + 2));
      if (v4[3]) bits |= (1ull << (j + 3));
    }
    mout[w] = bits;
    return;
  }
  int n4 = (y < 3) ? (4194304/4) : (1048576/4);
  int idx = blockIdx.x * 256 + threadIdx.x;
  if (idx >= n4) return;
  float4_t v = *(const float4_t*)(a.src[y] + (size_t)idx * 4);
  bf16x4 b; b[0]=(short)f2b(v[0]); b[1]=(short)f2b(v[1]); b[2]=(short)f2b(v[2]); b[3]=(short)f2b(v[3]);
  *(bf16x4*)(a.dst[y] + (size_t)idx * 4) = b;
}

// ---------------- QKV GEMM: BK=32 dbuf + counted vmcnt + XCD-chunked swizzle ----------
// 1D grid 768 = 8 XCD x 96. nid=(bid&7)*96+(bid>>3): each XCD owns 4 A-panels x all
// 24 (n,sel) -> A panels L2-resident with 24x reuse.
struct GemmArgs { const unsigned short* A[3]; const unsigned short* W[3];
                  const float* bias[3]; void* C[3]; };

__global__ __launch_bounds__(256) void gemm_qkv_kernel(GemmArgs ga)
{
  __shared__ unsigned short As[2*128*32];   // 2 x 8 KB
  __shared__ unsigned short Ws[2*128*32];   // 2 x 8 KB
  const int tid = threadIdx.x, lane = tid & 63, wid = tid >> 6;
  const int bid = blockIdx.x;
  const int nid = (bid & 7) * 96 + (bid >> 3);     // bijective (768 = 8*96)
  const int m0  = (nid / 24) * 128;
  const int rest = nid % 24;
  const int sel = rest >> 3;
  const int n0  = (rest & 7) * 128;
  const unsigned short* A = ga.A[sel];
  const unsigned short* W = ga.W[sel];
  const float* bias = ga.bias[sel];
  const int wm = wid >> 1, wn = wid & 1;
  const int r16 = lane & 15, kg = lane >> 4;
  const int phA = (kg ^ ((r16 >> 1) & 3)) * 8;     // phys chunk offset (ushorts)
  const int sRow = tid >> 2;                        // 0..63 within a 64-row round
  const int sL   = (tid & 3) ^ ((tid >> 3) & 3);    // logical chunk (round-invariant)

  f32x4 acc[4][4];
  const f32x4 z4 = {0.f, 0.f, 0.f, 0.f};
  #pragma unroll
  for (int i = 0; i < 4; ++i)
    #pragma unroll
    for (int j = 0; j < 4; ++j) acc[i][j] = z4;

  // prologue: stage k-step 0 into buf 0 (4 loads/thread)
  #pragma unroll
  for (int i = 0; i < 2; ++i){
    gload16(A + (size_t)(m0 + i*64 + sRow) * 1024 + sL * 8, (char*)As + i*4096 + wid*1024);
    gload16(W + (size_t)(n0 + i*64 + sRow) * 1024 + sL * 8, (char*)Ws + i*4096 + wid*1024);
  }

#define GSTEP(CUR, IT)                                                                \
  {                                                                                   \
    if ((IT) < 31) {                                                                  \
      const int k1 = ((IT) + 1) * 32;                                                 \
      _Pragma("unroll")                                                               \
      for (int i = 0; i < 2; ++i){                                                    \
        gload16(A + (size_t)(m0 + i*64 + sRow) * 1024 + k1 + sL * 8,                  \
                (char*)As + ((CUR) ^ 1) * 8192 + i*4096 + wid*1024);                  \
        gload16(W + (size_t)(n0 + i*64 + sRow) * 1024 + k1 + sL * 8,                  \
                (char*)Ws + ((CUR) ^ 1) * 8192 + i*4096 + wid*1024);                  \
      }                                                                               \
      asm volatile("s_waitcnt vmcnt(4)" ::: "memory");                                \
    } else {                                                                          \
      asm volatile("s_waitcnt vmcnt(0)" ::: "memory");                                \
    }                                                                                 \
    __builtin_amdgcn_sched_barrier(0);                                                \
    __builtin_amdgcn_s_barrier();      /* all threads' buf-CUR loads complete */      \
    bf16x8 af[4], wf[4];                                                              \
    _Pragma("unroll")                                                                 \
    for (int mi = 0; mi < 4; ++mi)                                                    \
      af[mi] = *(const bf16x8*)(As + (CUR)*4096 + (wm*64 + mi*16 + r16)*32 + phA);    \
    _Pragma("unroll")                                                                 \
    for (int ni = 0; ni < 4; ++ni)                                                    \
      wf[ni] = *(const bf16x8*)(Ws + (CUR)*4096 + (wn*64 + ni*16 + r16)*32 + phA);    \
    __builtin_amdgcn_s_setprio(1);                                                    \
    _Pragma("unroll")                                                                 \
    for (int mi = 0; mi < 4; ++mi)                                                    \
      _Pragma("unroll")                                                               \
      for (int ni = 0; ni < 4; ++ni)                                                  \
        acc[mi][ni] = __builtin_amdgcn_mfma_f32_16x16x32_bf16(af[mi], wf[ni],         \
                                                              acc[mi][ni], 0, 0, 0); \
    __builtin_amdgcn_s_setprio(0);                                                    \
    __builtin_amdgcn_s_barrier();      /* reads done before buf-CUR overwrite */      \
  }

  for (int ii = 0; ii < 16; ++ii) {
    GSTEP(0, 2 * ii)
    GSTEP(1, 2 * ii + 1)
  }
#undef GSTEP

  #pragma unroll
  for (int mi = 0; mi < 4; ++mi){
    #pragma unroll
    for (int ni = 0; ni < 4; ++ni){
      int m = m0 + wm*64 + mi*16 + kg*4;
      int n = n0 + wn*64 + ni*16 + r16;
      float bv = bias[n];
      if (sel == 2){
        int bb = m >> 11, t = m & 2047, hh = n >> 6, d = n & 63;
        bf16x4 pk;
        #pragma unroll
        for (int r = 0; r < 4; ++r) pk[r] = (short)f2b(acc[mi][ni][r] + bv);
        *(bf16x4*)&((unsigned short*)ga.C[2])[((size_t)(bb*16 + hh) * 64 + d) * 2048 + t] = pk;
      } else {
        #pragma unroll
        for (int r = 0; r < 4; ++r){
          float v = acc[mi][ni][r] + bv;
          if (sel == 0) v *= QSCALE;
          int mm = m + r;
          int bb = mm >> 11, t = mm & 2047, hh = n >> 6, d = n & 63;
          ((unsigned short*)ga.C[sel])[(((size_t)(bb*16 + hh) * 2048 + t) << 6) + d] = f2b(v);
        }
      }
    }
  }
}

// ---------------- O-proj GEMM: BM=64, BK=32 dbuf + counted vmcnt + XCD swizzle --------
__global__ __launch_bounds__(256) void gemm_o_kernel(const unsigned short* __restrict__ A,
    const unsigned short* __restrict__ W, const float* __restrict__ bias,
    float* __restrict__ C)
{
  __shared__ unsigned short As[2*64*32];    // 2 x 4 KB
  __shared__ unsigned short Ws[2*128*32];   // 2 x 8 KB
  const int tid = threadIdx.x, lane = tid & 63, wid = tid >> 6;
  const int bid = blockIdx.x;
  const int nid = (bid & 7) * 64 + (bid >> 3);     // bijective (512 = 8*64)
  const int m0 = (nid >> 3) * 64;
  const int n0 = (nid & 7) * 128;
  const int wm = wid >> 1, wn = wid & 1;
  const int r16 = lane & 15, kg = lane >> 4;
  const int phA = (kg ^ ((r16 >> 1) & 3)) * 8;
  const int sRow = tid >> 2;                        // 0..63
  const int sL   = (tid & 3) ^ ((tid >> 3) & 3);

  f32x4 acc[2][4];
  const f32x4 z4 = {0.f, 0.f, 0.f, 0.f};
  #pragma unroll
  for (int i = 0; i < 2; ++i)
    #pragma unroll
    for (int j = 0; j < 4; ++j) acc[i][j] = z4;

  // prologue: stage k-step 0 into buf 0 (3 loads/thread)
  gload16(A + (size_t)(m0 + sRow) * 1024 + sL * 8, (char*)As + wid*1024);
  #pragma unroll
  for (int i = 0; i < 2; ++i)
    gload16(W + (size_t)(n0 + i*64 + sRow) * 1024 + sL * 8, (char*)Ws + i*4096 + wid*1024);

#define OSTEP(CUR, IT)                                                                \
  {                                                                                   \
    if ((IT) < 31) {                                                                  \
      const int k1 = ((IT) + 1) * 32;                                                 \
      gload16(A + (size_t)(m0 + sRow) * 1024 + k1 + sL * 8,                           \
              (char*)As + ((CUR) ^ 1) * 4096 + wid*1024);                             \
      _Pragma("unroll")                                                               \
      for (int i = 0; i < 2; ++i)                                                     \
        gload16(W + (size_t)(n0 + i*64 + sRow) * 1024 + k1 + sL * 8,                  \
                (char*)Ws + ((CUR) ^ 1) * 8192 + i*4096 + wid*1024);                  \
      asm volatile("s_waitcnt vmcnt(3)" ::: "memory");                                \
    } else {                                                                          \
      asm volatile("s_waitcnt vmcnt(0)" ::: "memory");                                \
    }                                                                                 \
    __builtin_amdgcn_sched_barrier(0);                                                \
    __builtin_amdgcn_s_barrier();                                                     \
    bf16x8 af[2], wf[4];                                                              \
    _Pragma("unroll")                                                                 \
    for (int mi = 0; mi < 2; ++mi)                                                    \
      af[mi] = *(const bf16x8*)(As + (CUR)*2048 + (wm*32 + mi*16 + r16)*32 + phA);    \
    _Pragma("unroll")                                                                 \
    for (int ni = 0; ni < 4; ++ni)                                                    \
      wf[ni] = *(const bf16x8*)(Ws + (CUR)*4096 + (wn*64 + ni*16 + r16)*32 + phA);    \
    __builtin_amdgcn_s_setprio(1);                                                    \
    _Pragma("unroll")                                                                 \
    for (int mi = 0; mi < 2; ++mi)                                                    \
      _Pragma("unroll")                                                               \
      for (int ni = 0; ni < 4; ++ni)                                                  \
        acc[mi][ni] = __builtin_amdgcn_mfma_f32_16x16x32_bf16(af[mi], wf[ni],         \
                                                              acc[mi][ni], 0, 0, 0); \
    __builtin_amdgcn_s_setprio(0);                                                    \
    __builtin_amdgcn_s_barrier();                                                     \
  }

  for (int ii = 0; ii < 16; ++ii) {
    OSTEP(0, 2 * ii)
    OSTEP(1, 2 * ii + 1)
  }
#undef OSTEP

  #pragma unroll
  for (int mi = 0; mi < 2; ++mi){
    #pragma unroll
    for (int ni = 0; ni < 4; ++ni){
      int m = m0 + wm*32 + mi*16 + kg*4;
      int n = n0 + wn*64 + ni*16 + r16;
      float bv = bias[n];
      #pragma unroll
      for (int r = 0; r < 4; ++r)
        C[(size_t)(m + r) * 1024 + n] = acc[mi][ni][r] + bv;
    }
  }
}

// ---------------- flash attention (r15 pipeline + XCD-chunked swizzle) ----------------
// 1D grid 512 = 8 XCD x 64; nid=(bid&7)*64+(bid>>3): each XCD owns 4 bh x 16 t-blocks
// -> that bh's K/V (2 MB) stays L2-resident with 16x reuse.
__global__ __launch_bounds__(512) void attn_kernel(const unsigned short* __restrict__ qh,
    const unsigned short* __restrict__ kh, const unsigned short* __restrict__ vhT,
    const unsigned long long* __restrict__ mbits, unsigned short* __restrict__ attnout)
{
  __shared__ short Ks[2][2][64][64];   // [buf][sub][s][d]
  __shared__ short Vs[2][2][64][64];   // [buf][sub][d][s]
  __shared__ short Ps[128][64];        // wave-private 16-row stripes
  const int tid = threadIdx.x, lane = tid & 63, wid = tid >> 6;
  const int bid = blockIdx.x;
  const int nid = (bid & 7) * 64 + (bid >> 3);     // bijective (512 = 8*64)
  const int bh = nid >> 4;
  const int b = bh >> 4, h = bh & 15;
  const int t0 = (nid & 15) * 128;
  const int tw = t0 + wid * 16;
  const int r16 = lane & 15, kg = lane >> 4;
  const int x7 = r16 & 7;
  const int ph0 = (kg ^ x7) * 8;
  const int ph1 = ((kg + 4) ^ x7) * 8;
  const int sR = tid >> 3;             // 0..63
  const int sL = (tid & 7) ^ (sR & 7);

  const unsigned short* kbase = kh + (size_t)bh * 2048 * 64;
  const unsigned short* vtb   = vhT + (size_t)bh * 64 * 2048;
  const unsigned short* qbase = qh + ((size_t)bh * 2048 + tw) * 64;

  bf16x8 aq[2];
  aq[0] = *(const bf16x8*)(qbase + (size_t)r16 * 64 + kg * 8);
  aq[1] = *(const bf16x8*)(qbase + (size_t)r16 * 64 + 32 + kg * 8);

  const short ob = (short)0x3F80;
  const bf16x8 ones8 = {ob, ob, ob, ob, ob, ob, ob, ob};

  f32x4 o[4], o5;
  const f32x4 z4 = {0.f, 0.f, 0.f, 0.f};
  #pragma unroll
  for (int df = 0; df < 4; ++df) o[df] = z4;
  o5 = z4;

  const unsigned long long* mrow = mbits + (size_t)(tw + r16) * 32;
  const size_t koff = (size_t)sR * 64 + sL * 8;
  const size_t voff = (size_t)sR * 2048 + sL * 8;

  // prologue: stage KV block 0 into buf 0
  #pragma unroll
  for (int i = 0; i < 2; ++i){
    gload16(kbase + (size_t)i * 4096 + koff, (char*)Ks + i * 8192 + wid * 1024);
    gload16(vtb + voff + i * 64,            (char*)Vs + i * 8192 + wid * 1024);
  }
  u64x2 mw = *(const u64x2*)(mrow);
  __syncthreads();

#define ATTN_STEP(CUR, IT)                                                            \
  {                                                                                   \
    u64x2 mwn = mw;                                                                   \
    if ((IT) < 15) {                                                                  \
      const unsigned short* kc = kbase + (size_t)((IT) + 1) * 8192;                   \
      const unsigned short* vc = vtb + (size_t)((IT) + 1) * 128;                      \
      _Pragma("unroll")                                                               \
      for (int i = 0; i < 2; ++i){                                                    \
        gload16(kc + (size_t)i * 4096 + koff,                                         \
                (char*)Ks + ((CUR) ^ 1) * 16384 + i * 8192 + wid * 1024);             \
        gload16(vc + voff + i * 64,                                                   \
                (char*)Vs + ((CUR) ^ 1) * 16384 + i * 8192 + wid * 1024);             \
      }                                                                               \
      mwn = *(const u64x2*)(mrow + 2 * ((IT) + 1));                                   \
    }                                                                                 \
    _Pragma("unroll")                                                                 \
    for (int sub = 0; sub < 2; ++sub){                                                \
      f32x4 sfr[4];                                                                   \
      __builtin_amdgcn_s_setprio(1);                                                  \
      _Pragma("unroll")                                                               \
      for (int sb = 0; sb < 4; ++sb){                                                 \
        bf16x8 bk0 = *(const bf16x8*)&Ks[CUR][sub][sb*16 + r16][ph0];                 \
        bf16x8 bk1 = *(const bf16x8*)&Ks[CUR][sub][sb*16 + r16][ph1];                 \
        f32x4 z = z4;                                                                 \
        z = __builtin_amdgcn_mfma_f32_16x16x32_bf16(bk0, aq[0], z, 0, 0, 0);          \
        z = __builtin_amdgcn_mfma_f32_16x16x32_bf16(bk1, aq[1], z, 0, 0, 0);          \
        sfr[sb] = z;                                                                  \
      }                                                                               \
      __builtin_amdgcn_s_setprio(0);                                                  \
      {                                                                               \
        unsigned long long mk = (~mw[sub]) >> (kg * 4);   /* 1 = keep */              \
        unsigned int wlo = (unsigned int)mk;                                          \
        unsigned int whi = (unsigned int)(mk >> 32);                                  \
        _Pragma("unroll")                                                             \
        for (int sb = 0; sb < 4; ++sb){                                               \
          unsigned int wd = (sb < 2) ? wlo : whi;                                     \
          float pf[4];                                                                \
          _Pragma("unroll")                                                           \
          for (int r = 0; r < 4; ++r){                                                \
            const int pos = (sb & 1) * 16 + r;                                        \
            unsigned int msk = (unsigned int)((int)(wd << (31 - pos)) >> 31);         \
            float e = EXP2R(sfr[sb][r]);                                              \
            pf[r] = __builtin_bit_cast(float,                                         \
                      __builtin_bit_cast(unsigned int, e) & msk);                     \
          }                                                                           \
          unsigned int lo = cvtpk_bf16(pf[0], pf[1]);                                 \
          unsigned int hi = cvtpk_bf16(pf[2], pf[3]);                                 \
          int phys = (sb * 2 + (kg >> 1)) ^ x7;                                       \
          uint2_t pk; pk[0] = lo; pk[1] = hi;                                         \
          *(uint2_t*)&Ps[wid*16 + r16][phys * 8 + (kg & 1) * 4] = pk;                 \
        }                                                                             \
      }                                                                               \
      bf16x8 pa0 = *(const bf16x8*)&Ps[wid*16 + r16][ph0];                            \
      bf16x8 pa1 = *(const bf16x8*)&Ps[wid*16 + r16][ph1];                            \
      __builtin_amdgcn_s_setprio(1);                                                  \
      _Pragma("unroll")                                                               \
      for (int df = 0; df < 4; ++df){                                                 \
        bf16x8 bv0 = *(const bf16x8*)&Vs[CUR][sub][df*16 + r16][ph0];                 \
        bf16x8 bv1 = *(const bf16x8*)&Vs[CUR][sub][df*16 + r16][ph1];                 \
        o[df] = __builtin_amdgcn_mfma_f32_16x16x32_bf16(pa0, bv0, o[df], 0, 0, 0);    \
        o[df] = __builtin_amdgcn_mfma_f32_16x16x32_bf16(pa1, bv1, o[df], 0, 0, 0);    \
      }                                                                               \
      o5 = __builtin_amdgcn_mfma_f32_16x16x32_bf16(pa0, ones8, o5, 0, 0, 0);          \
      o5 = __builtin_amdgcn_mfma_f32_16x16x32_bf16(pa1, ones8, o5, 0, 0, 0);          \
      __builtin_amdgcn_s_setprio(0);                                                  \
    }                                                                                 \
    __syncthreads();                                                                  \
    mw = mwn;                                                                         \
  }

  for (int ii = 0; ii < 8; ++ii) {
    ATTN_STEP(0, 2 * ii)
    ATTN_STEP(1, 2 * ii + 1)
  }
#undef ATTN_STEP

  // epilogue: every lane holds all 4 row-sums in o5
  float lv0 = 1.0f / o5[0];
  float lv1 = 1.0f / o5[1];
  float lv2 = 1.0f / o5[2];
  float lv3 = 1.0f / o5[3];
  #pragma unroll
  for (int df = 0; df < 4; ++df){
    int col = h*64 + df*16 + r16;
    int t = tw + kg*4;
    attnout[(size_t)(b * 2048 + t + 0) * 1024 + col] = (short)f2b(o[df][0] * lv0);
    attnout[(size_t)(b * 2048 + t + 1) * 1024 + col] = (short)f2b(o[df][1] * lv1);
    attnout[(size_t)(b * 2048 + t + 2) * 1024 + col] = (short)f2b(o[df][2] * lv2);
    attnout[(size_t)(b * 2048 + t + 3) * 1024 + col] = (short)f2b(o[df][3] * lv3);
  }
}

// ---------------- launch ----------------
extern "C" void kernel_launch(void* const* d_in, const int* in_sizes, int n_in,
                              void* d_out, int out_size, void* d_ws, size_t ws_size,
                              hipStream_t stream) {
  const float* q    = (const float*)d_in[0];
  const float* k    = (const float*)d_in[1];
  const float* v    = (const float*)d_in[2];
  const int*   mask = (const int*)d_in[3];
  const float* Wq = (const float*)d_in[4];  const float* bq = (const float*)d_in[5];
  const float* Wk = (const float*)d_in[6];  const float* bk = (const float*)d_in[7];
  const float* Wv = (const float*)d_in[8];  const float* bv = (const float*)d_in[9];
  const float* Wo = (const float*)d_in[10]; const float* bo = (const float*)d_in[11];

  char* ws = (char*)d_ws;
  unsigned short* qb   = (unsigned short*)(ws);                   // 8 MB [4096][1024] bf16
  unsigned short* kb   = (unsigned short*)(ws + 8388608);         // 8 MB
  unsigned short* vb   = (unsigned short*)(ws + 16777216);        // 8 MB
  unsigned short* Wqb  = (unsigned short*)(ws + 25165824);        // 2 MB
  unsigned short* Wkb  = (unsigned short*)(ws + 27262976);        // 2 MB
  unsigned short* Wvb  = (unsigned short*)(ws + 29360128);        // 2 MB
  unsigned short* Wob  = (unsigned short*)(ws + 31457280);        // 2 MB
  unsigned short* qhd  = (unsigned short*)(ws + 33554432);        // 8 MB [bh][t][64]
  unsigned short* khd  = (unsigned short*)(ws + 41943040);        // 8 MB [bh][s][64]
  unsigned short* vhT  = (unsigned short*)(ws + 50331648);        // 8 MB [bh][64][2048]
  unsigned long long* mbits = (unsigned long long*)(ws + 58720256); // 512 KB
  unsigned short* attno = qb;   // alias: qb dead after QKV GEMM

  CvtArgs ca;
  ca.src[0]=q;  ca.dst[0]=qb;  ca.src[1]=k;  ca.dst[1]=kb;  ca.src[2]=v;  ca.dst[2]=vb;
  ca.src[3]=Wq; ca.dst[3]=Wqb; ca.src[4]=Wk; ca.dst[4]=Wkb;
  ca.src[5]=Wv; ca.dst[5]=Wvb; ca.src[6]=Wo; ca.dst[6]=Wob;
  cvt_kernel<<<dim3(4096, 8), 256, 0, stream>>>(ca, mask, mbits);

  GemmArgs g0;
  g0.A[0]=qb; g0.A[1]=kb; g0.A[2]=vb;
  g0.W[0]=Wqb; g0.W[1]=Wkb; g0.W[2]=Wvb;
  g0.bias[0]=bq; g0.bias[1]=bk; g0.bias[2]=bv;
  g0.C[0]=qhd; g0.C[1]=khd; g0.C[2]=vhT;
  gemm_qkv_kernel<<<768, 256, 0, stream>>>(g0);

  attn_kernel<<<512, 512, 0, stream>>>(qhd, khd, vhT, mbits, attno);

  gemm_o_kernel<<<512, 256, 0, stream>>>(attno, Wob, bo, (float*)d_out);
}